// Round 6
// baseline (256.013 us; speedup 1.0000x reference)
//
#include <hip/hip_runtime.h>
#include <math.h>

typedef __fp16   fp16x2  __attribute__((ext_vector_type(2)));
typedef _Float16 half8   __attribute__((ext_vector_type(8)));
typedef float    floatx4 __attribute__((ext_vector_type(4)));

#define M_TOTAL 16384
#define K_DIM   2048
#define NCOL    128
#define BM      16
#define BK      32
#define NT      256
#define NCHUNK  (K_DIM / BK)   // 64

// halves offsets within one LDS buffer (BM=16)
// layout: [Ahi 512][Alo 512][Bhi 4096][Blo 4096] halves = 18432 B
#define A_HI  0
#define A_LO  512
#define B_HI  1024
#define B_LO  5120
#define BUF_H 9216

__device__ __forceinline__ void gl_lds16(const _Float16* g, _Float16* l) {
    __builtin_amdgcn_global_load_lds((const __attribute__((address_space(1))) void*)g,
                                     (__attribute__((address_space(3))) void*)l, 16, 0, 0);
}

// convert 2 fp32 -> hi/lo f16 pairs, store 4B each
__device__ __forceinline__ void cvt_store2(const float2 v, _Float16* hiP, _Float16* loP) {
    fp16x2 h = __builtin_amdgcn_cvt_pkrtz(v.x, v.y);
    float r0 = (v.x - (float)h.x) * 2048.0f;
    float r1 = (v.y - (float)h.y) * 2048.0f;
    fp16x2 l = __builtin_amdgcn_cvt_pkrtz(r0, r1);
    union { fp16x2 h2; unsigned u; } ph, pl;
    ph.h2 = h; pl.h2 = l;
    *(unsigned*)hiP = ph.u;
    *(unsigned*)loP = pl.u;
}

// Pre-convert W (router||noise, fp32 [128][2048]) into ws as hi/lo f16,
// granule-major per 32-k chunk: chunk c = 8192 halves:
//   hi: [(g*128 + col)*8 + j]  (g=0..3 k-granule, col=0..127, j=0..7)
//   lo: same at +4096 halves
__global__ __launch_bounds__(256) void conv_w_kernel(
    const float* __restrict__ rw, const float* __restrict__ nw,
    _Float16* __restrict__ wsB)
{
    const int u   = blockIdx.x * 256 + threadIdx.x;  // 0..32767
    const int col = u & 127;
    const int g   = (u >> 7) & 3;
    const int c   = u >> 9;
    const float* srcRow = (col < 64) ? (rw + (size_t)col * K_DIM)
                                     : (nw + (size_t)(col - 64) * K_DIM);
    const float* src = srcRow + c * BK + g * 8;
    const float4 v0 = *(const float4*)src;
    const float4 v1 = *(const float4*)(src + 4);
    union { fp16x2 h[4]; uint4 q; } ph, pl;
    ph.h[0] = __builtin_amdgcn_cvt_pkrtz(v0.x, v0.y);
    ph.h[1] = __builtin_amdgcn_cvt_pkrtz(v0.z, v0.w);
    ph.h[2] = __builtin_amdgcn_cvt_pkrtz(v1.x, v1.y);
    ph.h[3] = __builtin_amdgcn_cvt_pkrtz(v1.z, v1.w);
    pl.h[0] = __builtin_amdgcn_cvt_pkrtz((v0.x - (float)ph.h[0].x) * 2048.0f,
                                         (v0.y - (float)ph.h[0].y) * 2048.0f);
    pl.h[1] = __builtin_amdgcn_cvt_pkrtz((v0.z - (float)ph.h[1].x) * 2048.0f,
                                         (v0.w - (float)ph.h[1].y) * 2048.0f);
    pl.h[2] = __builtin_amdgcn_cvt_pkrtz((v1.x - (float)ph.h[2].x) * 2048.0f,
                                         (v1.y - (float)ph.h[2].y) * 2048.0f);
    pl.h[3] = __builtin_amdgcn_cvt_pkrtz((v1.z - (float)ph.h[3].x) * 2048.0f,
                                         (v1.w - (float)ph.h[3].y) * 2048.0f);
    const size_t base = (size_t)c * 8192 + ((size_t)g * 128 + col) * 8;
    *(uint4*)&wsB[base]        = ph.q;
    *(uint4*)&wsB[base + 4096] = pl.q;
}

// r0-verified template at BM=16: grid 1024 -> 4 blocks/CU (LDS 36.9KB x4 fits),
// 16 waves/CU. Per wave: 16 rows x 32 cols, 6 ds_read_b128 + 6 MFMA / chunk.
// The per-chunk barrier stall of one block is covered by the other 3 blocks.
__global__ __launch_bounds__(NT, 4) void gemm_router_kernel(
    const float* __restrict__ x,
    const _Float16* __restrict__ wsB,
    const float* __restrict__ router_b,
    const float* __restrict__ noise_b,
    const float* __restrict__ noise_u,
    float* __restrict__ out)
{
    __shared__ __align__(16) union {
        _Float16 S[2 * BUF_H];   // 36864 B
        struct { float Cs[16][132]; float p1[16]; float p2[16]; int i1[16]; int i2[16]; } e;
    } sm;

    const int t    = threadIdx.x;
    const int lane = t & 63;
    const int w    = t >> 6;
    const int rowBase = blockIdx.x * BM;

    // A staging map: thread -> (row rr 0..15, float2 index q2 0..15) fully coalesced
    const int rr = t >> 4, q2 = t & 15;
    const float* pa = x + (size_t)(rowBase + rr) * K_DIM + q2 * 2;
    // granule g = (q2*2)/8, j = (q2*2)%8 ; layout [g][row][8]
    const int aw = (((q2 >> 2) * 16 + rr) * 8) + ((q2 & 3) * 2);

    // fragment map: wave w -> rows 0..15, cols w*32..w*32+31
    const int lr  = lane & 15;
    const int lg4 = lane >> 4;
    const int nt0 = w * 32;
    const int aOff = (lg4 * 16 + lr) * 8;

    floatx4 acch[2], accx[2];
    #pragma unroll
    for (int ni = 0; ni < 2; ++ni) { acch[ni] = (floatx4)0.0f; accx[ni] = (floatx4)0.0f; }

    // prologue: stage B(0) (4 gl_lds/wave cover full 16KB chunk) + A(0)
    {
        #pragma unroll
        for (int i = 0; i < 4; ++i) {
            const int n = w * 4 + i;
            gl_lds16(wsB + n * 512 + lane * 8, &sm.S[B_HI + n * 512]);
        }
    }
    {
        const float2 a0 = *(const float2*)pa;
        cvt_store2(a0, &sm.S[A_HI + aw], &sm.S[A_LO + aw]);
    }

    for (int c = 0; c < NCHUNK; ++c) {
        __syncthreads();  // B(c) arrived, A(c) staged, buf[(c+1)&1] reads done
        _Float16* buf  = sm.S + (c & 1) * BUF_H;
        _Float16* bufn = sm.S + ((c + 1) & 1) * BUF_H;

        float2 aReg;
        if (c + 1 < NCHUNK) {
            const _Float16* wc = wsB + (size_t)(c + 1) * 8192;
            #pragma unroll
            for (int i = 0; i < 4; ++i) {
                const int n = w * 4 + i;
                gl_lds16(wc + n * 512 + lane * 8, bufn + B_HI + n * 512);
            }
            aReg = *(const float2*)(pa + (c + 1) * BK);
        }

        const half8 ah = *(const half8*)&buf[A_HI + aOff];
        const half8 al = *(const half8*)&buf[A_LO + aOff];
        half8 bh[2], bl[2];
        #pragma unroll
        for (int ni = 0; ni < 2; ++ni) {
            const int bo = (lg4 * 128 + nt0 + ni * 16 + lr) * 8;
            bh[ni] = *(const half8*)&buf[B_HI + bo];
            bl[ni] = *(const half8*)&buf[B_LO + bo];
        }
        #pragma unroll
        for (int ni = 0; ni < 2; ++ni) {
            acch[ni] = __builtin_amdgcn_mfma_f32_16x16x32_f16(ah, bh[ni], acch[ni], 0, 0, 0);
            accx[ni] = __builtin_amdgcn_mfma_f32_16x16x32_f16(ah, bl[ni], accx[ni], 0, 0, 0);
            accx[ni] = __builtin_amdgcn_mfma_f32_16x16x32_f16(al, bh[ni], accx[ni], 0, 0, 0);
        }
        if (c + 1 < NCHUNK)
            cvt_store2(aReg, &bufn[A_HI + aw], &bufn[A_LO + aw]);
    }

    // ---- fused epilogue ----
    // chunk 63 used buf1 (bytes 18432..); Cs occupies bytes 0..8448 -> no race
    #pragma unroll
    for (int ni = 0; ni < 2; ++ni) {
        const floatx4 v = acch[ni] + accx[ni] * (1.0f / 2048.0f);
        const int col = nt0 + ni * 16 + lr;
        #pragma unroll
        for (int reg = 0; reg < 4; ++reg)
            sm.e.Cs[lg4 * 4 + reg][col] = v[reg];
    }
    __syncthreads();

    // per-row top-2: 8 threads/row, 8 experts each, shuffle merge (t<128)
    if (t < 128) {
        const int sr = t >> 3;          // row 0..15
        const int eg = (t & 7) * 8;     // expert base
        const int grow = rowBase + sr;
        const float* urow = noise_u + (size_t)grow * 64 + eg;
        const float4 u0 = *(const float4*)urow;
        const float4 u1 = *(const float4*)(urow + 4);
        const float uu[8] = {u0.x, u0.y, u0.z, u0.w, u1.x, u1.y, u1.z, u1.w};
        float v1 = -3.0e38f, v2 = -3.0e38f;
        int i1 = 0, i2 = 0;
        #pragma unroll
        for (int j = 0; j < 8; ++j) {
            const int e = eg + j;
            const float lg = sm.e.Cs[sr][e] + router_b[e];
            const float nz = sm.e.Cs[sr][64 + e] + noise_b[e];
            const float sp = fmaxf(nz, 0.0f) + log1pf(expf(-fabsf(nz)));
            const float nv = lg + sp * uu[j];
            if (nv > v1)      { v2 = v1; i2 = i1; v1 = nv; i1 = e; }
            else if (nv > v2) { v2 = nv; i2 = e; }
        }
        #pragma unroll
        for (int m = 1; m < 8; m <<= 1) {
            const float ov1 = __shfl_xor(v1, m, 64);
            const int   oi1 = __shfl_xor(i1, m, 64);
            const float ov2 = __shfl_xor(v2, m, 64);
            const int   oi2 = __shfl_xor(i2, m, 64);
            const bool takeO = (ov1 > v1) || (ov1 == v1 && oi1 < i1);
            const float t1v = takeO ? ov1 : v1;  const int t1i = takeO ? oi1 : i1;
            const float c2v = takeO ? v1 : ov1;  const int c2i = takeO ? i1 : oi1;
            const float c3v = takeO ? ov2 : v2;  const int c3i = takeO ? oi2 : i2;
            const bool k2 = (c3v > c2v) || (c3v == c2v && c3i < c2i);
            v1 = t1v; i1 = t1i;
            v2 = k2 ? c3v : c2v; i2 = k2 ? c3i : c2i;
        }
        if ((t & 7) == 0) {
            const float e2 = expf(v2 - v1);
            const float dn = 1.0f + e2;   // other 62 slots: exp(-1e30 - m) == 0
            sm.e.p1[sr] = 1.0f / dn;
            sm.e.p2[sr] = e2 / dn;
            sm.e.i1[sr] = i1;
            sm.e.i2[sr] = i2;
            float2 idx2;
            idx2.x = (float)i1;
            idx2.y = (float)i2;
            *(float2*)&out[(size_t)M_TOTAL * 64 + (size_t)grow * 2] = idx2;
        }
    }
    __syncthreads();

    // cooperative sparse-softmax write: 16 rows x 64 experts, 8 floats/thread (t<128)
    if (t < 128) {
        const int r2 = t >> 3;
        const int e0 = (t & 7) * 8;
        const int g2 = rowBase + r2;
        const int j1 = sm.e.i1[r2], j2 = sm.e.i2[r2];
        const float q1 = sm.e.p1[r2], q2v = sm.e.p2[r2];
        float* orow = out + (size_t)g2 * 64;
        #pragma unroll
        for (int g = 0; g < 2; ++g) {
            const int b0 = e0 + g * 4;
            float4 v;
            v.x = (b0 + 0 == j1) ? q1 : (b0 + 0 == j2) ? q2v : 0.0f;
            v.y = (b0 + 1 == j1) ? q1 : (b0 + 1 == j2) ? q2v : 0.0f;
            v.z = (b0 + 2 == j1) ? q1 : (b0 + 2 == j2) ? q2v : 0.0f;
            v.w = (b0 + 3 == j1) ? q1 : (b0 + 3 == j2) ? q2v : 0.0f;
            *(float4*)&orow[b0] = v;
        }
    }
}

extern "C" void kernel_launch(void* const* d_in, const int* in_sizes, int n_in,
                              void* d_out, int out_size, void* d_ws, size_t ws_size,
                              hipStream_t stream) {
    const float* x  = (const float*)d_in[0];
    const float* rw = (const float*)d_in[1];
    const float* rb = (const float*)d_in[2];
    const float* nw = (const float*)d_in[3];
    const float* nb = (const float*)d_in[4];
    const float* nu = (const float*)d_in[5];
    float* out = (float*)d_out;
    _Float16* wsB = (_Float16*)d_ws;
    (void)in_sizes; (void)n_in; (void)out_size; (void)ws_size;

    hipLaunchKernelGGL(conv_w_kernel, dim3(128), dim3(256), 0, stream, rw, nw, wsB);
    hipLaunchKernelGGL(gemm_router_kernel, dim3(M_TOTAL / BM), dim3(NT), 0, stream,
                       x, wsB, rb, nb, nu, out);
}

// Round 7
// 249.455 us; speedup vs baseline: 1.0263x; 1.0263x over previous
//
#include <hip/hip_runtime.h>
#include <math.h>

typedef __fp16   fp16x2  __attribute__((ext_vector_type(2)));
typedef _Float16 half8   __attribute__((ext_vector_type(8)));
typedef float    floatx4 __attribute__((ext_vector_type(4)));

#define M_TOTAL 16384
#define K_DIM   2048
#define BM      32
#define NT      256
#define NCHUNK  64

// Pre-convert W (router||noise, fp32 [128][2048]) into ws as hi/lo f16,
// granule-major per 32-k chunk: chunk c = 8192 halves:
//   hi: [(g*128 + col)*8 + j]  (g=0..3 k-granule, col=0..127, j=0..7)
//   lo: same at +4096 halves
__global__ __launch_bounds__(256) void conv_w_kernel(
    const float* __restrict__ rw, const float* __restrict__ nw,
    _Float16* __restrict__ wsB)
{
    const int u   = blockIdx.x * 256 + threadIdx.x;  // 0..32767
    const int col = u & 127;
    const int g   = (u >> 7) & 3;
    const int c   = u >> 9;
    const float* srcRow = (col < 64) ? (rw + (size_t)col * K_DIM)
                                     : (nw + (size_t)(col - 64) * K_DIM);
    const float* src = srcRow + c * 32 + g * 8;
    const float4 v0 = *(const float4*)src;
    const float4 v1 = *(const float4*)(src + 4);
    union { fp16x2 h[4]; uint4 q; } ph, pl;
    ph.h[0] = __builtin_amdgcn_cvt_pkrtz(v0.x, v0.y);
    ph.h[1] = __builtin_amdgcn_cvt_pkrtz(v0.z, v0.w);
    ph.h[2] = __builtin_amdgcn_cvt_pkrtz(v1.x, v1.y);
    ph.h[3] = __builtin_amdgcn_cvt_pkrtz(v1.z, v1.w);
    pl.h[0] = __builtin_amdgcn_cvt_pkrtz((v0.x - (float)ph.h[0].x) * 2048.0f,
                                         (v0.y - (float)ph.h[0].y) * 2048.0f);
    pl.h[1] = __builtin_amdgcn_cvt_pkrtz((v0.z - (float)ph.h[1].x) * 2048.0f,
                                         (v0.w - (float)ph.h[1].y) * 2048.0f);
    pl.h[2] = __builtin_amdgcn_cvt_pkrtz((v1.x - (float)ph.h[2].x) * 2048.0f,
                                         (v1.y - (float)ph.h[2].y) * 2048.0f);
    pl.h[3] = __builtin_amdgcn_cvt_pkrtz((v1.z - (float)ph.h[3].x) * 2048.0f,
                                         (v1.w - (float)ph.h[3].y) * 2048.0f);
    const size_t base = (size_t)c * 8192 + ((size_t)g * 128 + col) * 8;
    *(uint4*)&wsB[base]        = ph.q;
    *(uint4*)&wsB[base + 4096] = pl.q;
}

// in-register fp32x8 -> hi/lo f16x8 split (path proven correct in r1)
__device__ __forceinline__ void cvt8(const float4 v0, const float4 v1,
                                     half8& hi, half8& lo) {
    union { fp16x2 h[4]; half8 v; } H, L;
    H.h[0] = __builtin_amdgcn_cvt_pkrtz(v0.x, v0.y);
    H.h[1] = __builtin_amdgcn_cvt_pkrtz(v0.z, v0.w);
    H.h[2] = __builtin_amdgcn_cvt_pkrtz(v1.x, v1.y);
    H.h[3] = __builtin_amdgcn_cvt_pkrtz(v1.z, v1.w);
    L.h[0] = __builtin_amdgcn_cvt_pkrtz((v0.x - (float)H.h[0].x) * 2048.0f,
                                        (v0.y - (float)H.h[0].y) * 2048.0f);
    L.h[1] = __builtin_amdgcn_cvt_pkrtz((v0.z - (float)H.h[1].x) * 2048.0f,
                                        (v0.w - (float)H.h[1].y) * 2048.0f);
    L.h[2] = __builtin_amdgcn_cvt_pkrtz((v1.x - (float)H.h[2].x) * 2048.0f,
                                        (v1.y - (float)H.h[2].y) * 2048.0f);
    L.h[3] = __builtin_amdgcn_cvt_pkrtz((v1.z - (float)H.h[3].x) * 2048.0f,
                                        (v1.w - (float)H.h[3].y) * 2048.0f);
    hi = H.v; lo = L.v;
}

// Zero-LDS, zero-barrier GEMM: wsB (1 MB) is L2/L3-resident and has no
// cross-wave reuse within a block -> LDS staging was pure overhead.
// Each wave independently computes 32 rows x 32 cols: A and B fragments
// loaded straight to registers (one-chunk prefetch), hi/lo cvt in-reg.
// Block = 32 rows x 128 cols (4 waves, wave w owns cols w*32..+31);
// the block must own full rows because the epilogue does top-2 per row.
__global__ __launch_bounds__(NT, 2) void gemm_router_kernel(
    const float* __restrict__ x,
    const _Float16* __restrict__ wsB,
    const float* __restrict__ router_b,
    const float* __restrict__ noise_b,
    const float* __restrict__ noise_u,
    float* __restrict__ out)
{
    __shared__ __align__(16) struct {
        float Cs[32][132]; float p1[32]; float p2[32]; int i1[32]; int i2[32];
    } sme;

    const int t    = threadIdx.x;
    const int lane = t & 63;
    const int w    = t >> 6;
    const int rowBase = blockIdx.x * BM;

    const int lr  = lane & 15;
    const int lg4 = lane >> 4;
    const int nt0 = w * 32;

    // per-lane fragment bases (same index algebra as the verified LDS reads)
    const float* pax = x + (size_t)(rowBase + lr) * K_DIM + lg4 * 8;
    const _Float16* pb = wsB + ((size_t)lg4 * 128 + nt0 + lr) * 8;

    floatx4 acch[2][2], accx[2][2];
    #pragma unroll
    for (int mi = 0; mi < 2; ++mi)
        #pragma unroll
        for (int ni = 0; ni < 2; ++ni) {
            acch[mi][ni] = (floatx4)0.0f;
            accx[mi][ni] = (floatx4)0.0f;
        }

    float4 aCur[4], aNxt[4];
    half8  bhC[2], blC[2], bhN[2], blN[2];

    // prologue: chunk 0 fragments
    #pragma unroll
    for (int mi = 0; mi < 2; ++mi)
        #pragma unroll
        for (int h = 0; h < 2; ++h)
            aCur[mi * 2 + h] = *(const float4*)(pax + mi * 16 * K_DIM + h * 4);
    #pragma unroll
    for (int ni = 0; ni < 2; ++ni) {
        bhC[ni] = *(const half8*)(pb + ni * 128);
        blC[ni] = *(const half8*)(pb + ni * 128 + 4096);
    }

    for (int c = 0; c < NCHUNK; ++c) {
        // issue chunk c+1 loads (independent of chunk-c compute; the
        // compiler keeps them in flight across the MFMA cluster)
        const int cn = (c + 1 < NCHUNK) ? c + 1 : NCHUNK - 1;
        const float* pan = pax + cn * 32;
        const _Float16* pbn = pb + (size_t)cn * 8192;
        #pragma unroll
        for (int mi = 0; mi < 2; ++mi)
            #pragma unroll
            for (int h = 0; h < 2; ++h)
                aNxt[mi * 2 + h] = *(const float4*)(pan + mi * 16 * K_DIM + h * 4);
        #pragma unroll
        for (int ni = 0; ni < 2; ++ni) {
            bhN[ni] = *(const half8*)(pbn + ni * 128);
            blN[ni] = *(const half8*)(pbn + ni * 128 + 4096);
        }

        half8 ah[2], al[2];
        cvt8(aCur[0], aCur[1], ah[0], al[0]);
        cvt8(aCur[2], aCur[3], ah[1], al[1]);

        __builtin_amdgcn_s_setprio(1);
        #pragma unroll
        for (int mi = 0; mi < 2; ++mi)
            #pragma unroll
            for (int ni = 0; ni < 2; ++ni) {
                acch[mi][ni] = __builtin_amdgcn_mfma_f32_16x16x32_f16(ah[mi], bhC[ni], acch[mi][ni], 0, 0, 0);
                accx[mi][ni] = __builtin_amdgcn_mfma_f32_16x16x32_f16(ah[mi], blC[ni], accx[mi][ni], 0, 0, 0);
                accx[mi][ni] = __builtin_amdgcn_mfma_f32_16x16x32_f16(al[mi], bhC[ni], accx[mi][ni], 0, 0, 0);
            }
        __builtin_amdgcn_s_setprio(0);

        #pragma unroll
        for (int i = 0; i < 4; ++i) aCur[i] = aNxt[i];
        #pragma unroll
        for (int ni = 0; ni < 2; ++ni) {
            bhC[ni] = bhN[ni]; blC[ni] = blN[ni];
        }
    }

    // ---- fused epilogue (unchanged from the verified r0 version) ----
    #pragma unroll
    for (int mi = 0; mi < 2; ++mi)
        #pragma unroll
        for (int ni = 0; ni < 2; ++ni) {
            const floatx4 v = acch[mi][ni] + accx[mi][ni] * (1.0f / 2048.0f);
            const int col = nt0 + ni * 16 + lr;
            #pragma unroll
            for (int reg = 0; reg < 4; ++reg)
                sme.Cs[mi * 16 + lg4 * 4 + reg][col] = v[reg];
        }
    __syncthreads();

    // per-row top-2: 8 threads/row, 8 experts each, shuffle merge
    {
        const int sr = t >> 3;          // row 0..31
        const int eg = (t & 7) * 8;     // expert base
        const int grow = rowBase + sr;
        const float* urow = noise_u + (size_t)grow * 64 + eg;
        const float4 u0 = *(const float4*)urow;
        const float4 u1 = *(const float4*)(urow + 4);
        const float uu[8] = {u0.x, u0.y, u0.z, u0.w, u1.x, u1.y, u1.z, u1.w};
        float v1 = -3.0e38f, v2 = -3.0e38f;
        int i1 = 0, i2 = 0;
        #pragma unroll
        for (int j = 0; j < 8; ++j) {
            const int e = eg + j;
            const float lg = sme.Cs[sr][e] + router_b[e];
            const float nz = sme.Cs[sr][64 + e] + noise_b[e];
            const float sp = fmaxf(nz, 0.0f) + log1pf(expf(-fabsf(nz)));
            const float nv = lg + sp * uu[j];
            if (nv > v1)      { v2 = v1; i2 = i1; v1 = nv; i1 = e; }
            else if (nv > v2) { v2 = nv; i2 = e; }
        }
        #pragma unroll
        for (int m = 1; m < 8; m <<= 1) {
            const float ov1 = __shfl_xor(v1, m, 64);
            const int   oi1 = __shfl_xor(i1, m, 64);
            const float ov2 = __shfl_xor(v2, m, 64);
            const int   oi2 = __shfl_xor(i2, m, 64);
            const bool takeO = (ov1 > v1) || (ov1 == v1 && oi1 < i1);
            const float t1v = takeO ? ov1 : v1;  const int t1i = takeO ? oi1 : i1;
            const float c2v = takeO ? v1 : ov1;  const int c2i = takeO ? i1 : oi1;
            const float c3v = takeO ? ov2 : v2;  const int c3i = takeO ? oi2 : i2;
            const bool k2 = (c3v > c2v) || (c3v == c2v && c3i < c2i);
            v1 = t1v; i1 = t1i;
            v2 = k2 ? c3v : c2v; i2 = k2 ? c3i : c2i;
        }
        if ((t & 7) == 0) {
            const float e2 = expf(v2 - v1);
            const float dn = 1.0f + e2;   // other 62 slots: exp(-1e30 - m) == 0
            sme.p1[sr] = 1.0f / dn;
            sme.p2[sr] = e2 / dn;
            sme.i1[sr] = i1;
            sme.i2[sr] = i2;
            float2 idx2;
            idx2.x = (float)i1;
            idx2.y = (float)i2;
            *(float2*)&out[(size_t)M_TOTAL * 64 + (size_t)grow * 2] = idx2;
        }
    }
    __syncthreads();

    // cooperative sparse-softmax write: 32 rows x 64 experts, 8 floats/thread
    {
        const int rr = t >> 3;
        const int e0 = (t & 7) * 8;
        const int g2 = rowBase + rr;
        const int j1 = sme.i1[rr], j2 = sme.i2[rr];
        const float q1 = sme.p1[rr], q2 = sme.p2[rr];
        float* orow = out + (size_t)g2 * 64;
        #pragma unroll
        for (int g = 0; g < 2; ++g) {
            const int b0 = e0 + g * 4;
            float4 v;
            v.x = (b0 + 0 == j1) ? q1 : (b0 + 0 == j2) ? q2 : 0.0f;
            v.y = (b0 + 1 == j1) ? q1 : (b0 + 1 == j2) ? q2 : 0.0f;
            v.z = (b0 + 2 == j1) ? q1 : (b0 + 2 == j2) ? q2 : 0.0f;
            v.w = (b0 + 3 == j1) ? q1 : (b0 + 3 == j2) ? q2 : 0.0f;
            *(float4*)&orow[b0] = v;
        }
    }
}

extern "C" void kernel_launch(void* const* d_in, const int* in_sizes, int n_in,
                              void* d_out, int out_size, void* d_ws, size_t ws_size,
                              hipStream_t stream) {
    const float* x  = (const float*)d_in[0];
    const float* rw = (const float*)d_in[1];
    const float* rb = (const float*)d_in[2];
    const float* nw = (const float*)d_in[3];
    const float* nb = (const float*)d_in[4];
    const float* nu = (const float*)d_in[5];
    float* out = (float*)d_out;
    _Float16* wsB = (_Float16*)d_ws;
    (void)in_sizes; (void)n_in; (void)out_size; (void)ws_size;

    hipLaunchKernelGGL(conv_w_kernel, dim3(128), dim3(256), 0, stream, rw, nw, wsB);
    hipLaunchKernelGGL(gemm_router_kernel, dim3(M_TOTAL / BM), dim3(NT), 0, stream,
                       x, wsB, rb, nb, nu, out);
}